// Round 5
// baseline (1802.127 us; speedup 1.0000x reference)
//
#include <hip/hip_runtime.h>
#include <math.h>

// LatentDynamics: out[b,t,:] = scan of h' = tanh(h*leak + sigmoid(h@Wh^T + z_t@Wz^T + b)*z_t)
// B=64, T=512, D=1024.
//
// Phase 0 (k_prep):   fp32->f16 of z and W (split Wh/Wz); init exchange slots (parity0 =
//                     h0 tag 0, parity1 = sentinel) -- re-run every launch (graph-safe).
// Phase 1 (k_gemm_zw): A[m,j] = z16[m,:]@Wz16^T[j,:] + bias[j] -> d_out (in-place slot for h).
// Phase 2 (k_recur):  256 persistent WGs = 16 groups (4 batches) x 16 ranks (64 j).
//                     Wh register-resident. h exchanged via fence-free tagged u64 slots
//                     ([tag32 | 2xf16], relaxed agent atomics). Wave w polls its k-quarter
//                     (8 u64/lane), stages to double-buffered LDS, then computes its OWN
//                     n-tile (16 j) over FULL K in-register (4 indep MFMA chains) --
//                     no cross-wave reduce, ONE barrier per step.

#define D_ 1024
#define B_ 64
#define T_ 512

typedef _Float16 f16;
typedef _Float16 f16x8 __attribute__((ext_vector_type(8)));
typedef _Float16 f16x4 __attribute__((ext_vector_type(4)));
typedef float f32x4 __attribute__((ext_vector_type(4)));
typedef unsigned long long u64;

// workspace layout (bytes); total 71,827,456 (~68.5 MB)
#define WS_Z16   0L
#define WS_WH16  67108864L
#define WS_WZ16  69206016L
#define WS_SLOTS 71303168L
// slots: u64[2][64][512]  (parity, batch, j-pair)

__device__ __forceinline__ void gload_lds16(const void* g, void* l) {
  __builtin_amdgcn_global_load_lds(
      (const __attribute__((address_space(1))) void*)(g),
      (__attribute__((address_space(3))) void*)(l), 16, 0, 0);
}

// ---------------------------------------------------------------- phase 0
__global__ __launch_bounds__(256) void k_prep(
    const float* __restrict__ z, const float* __restrict__ W,
    const float* __restrict__ h0, f16* __restrict__ z16,
    f16* __restrict__ wh16, f16* __restrict__ wz16, u64* __restrict__ slots) {
  const int tid = blockIdx.x * 256 + threadIdx.x;  // 2048*256 = 524288 threads
  const long ZN4 = 8388608, WN4 = 524288;
  for (long i = tid; i < ZN4 + WN4; i += 524288) {
    if (i < ZN4) {
      float4 v = *(const float4*)(z + i * 4);
      f16x4 o = {(f16)v.x, (f16)v.y, (f16)v.z, (f16)v.w};
      *(f16x4*)(z16 + i * 4) = o;
    } else {
      const long e2 = (i - ZN4) * 4;
      const long j = e2 >> 11, c = e2 & 2047;
      float4 v = *(const float4*)(W + e2);
      f16x4 o = {(f16)v.x, (f16)v.y, (f16)v.z, (f16)v.w};
      f16* dst = (c < D_) ? (wh16 + j * D_ + c) : (wz16 + j * D_ + (c - D_));
      *(f16x4*)dst = o;
    }
  }
  if (tid < 65536) {
    if (tid < 32768) {  // parity 0 <- h0, tag 0
      const int b = tid >> 9, p = tid & 511;
      f16 fa = (f16)h0[(long)b * D_ + 2 * p];
      f16 fb = (f16)h0[(long)b * D_ + 2 * p + 1];
      unsigned u = (unsigned)*(unsigned short*)&fa |
                   ((unsigned)*(unsigned short*)&fb << 16);
      slots[tid] = (u64)u;
    } else {
      slots[tid] = 0xFFFFFFFF00000000ull;  // parity 1 sentinel
    }
  }
}

// ---------------------------------------------------------------- phase 1
// 128x128 tile, 4 waves (2x2), BK=32, double-buffered LDS, both operands via
// global_load_lds (all-f16 path), 1 barrier per K-step.
__global__ __launch_bounds__(256) void k_gemm_zw(
    const f16* __restrict__ z16, const f16* __restrict__ wz16,
    const float* __restrict__ bias, float* __restrict__ out) {
  __shared__ f16 ldsA[2][8 * 512];
  __shared__ f16 ldsB[2][8 * 512];
  const int tid = threadIdx.x, lane = tid & 63, w = tid >> 6;
  const int r16 = lane & 15, g8 = lane >> 4;
  const int nt = blockIdx.x & 7, mt = blockIdx.x >> 3;
  const long m0 = (long)mt * 128, n0 = (long)nt * 128;
  const f16* gA = z16 + (m0 + r16) * D_ + g8 * 8;
  const f16* gB = wz16 + (n0 + r16) * D_ + g8 * 8;
  const int wr = w >> 1, wc = w & 1;
  f32x4 acc[4][4] = {};

#pragma unroll
  for (int c = 0; c < 2; ++c) {
    const int ch = w * 2 + c;
    gload_lds16(gA + (long)ch * 16 * D_, &ldsA[0][ch * 512]);
    gload_lds16(gB + (long)ch * 16 * D_, &ldsB[0][ch * 512]);
  }
  __syncthreads();

  for (int ks = 0; ks < 32; ++ks) {
    const int buf = ks & 1;
    if (ks < 31) {
#pragma unroll
      for (int c = 0; c < 2; ++c) {
        const int ch = w * 2 + c;
        gload_lds16(gA + (long)ch * 16 * D_ + (ks + 1) * 32, &ldsA[buf ^ 1][ch * 512]);
        gload_lds16(gB + (long)ch * 16 * D_ + (ks + 1) * 32, &ldsB[buf ^ 1][ch * 512]);
      }
    }
    f16x8 af[4], bf[4];
#pragma unroll
    for (int i = 0; i < 4; ++i)
      af[i] = *(const f16x8*)(&ldsA[buf][(wr * 4 + i) * 512 + lane * 8]);
#pragma unroll
    for (int j = 0; j < 4; ++j)
      bf[j] = *(const f16x8*)(&ldsB[buf][(wc * 4 + j) * 512 + lane * 8]);
#pragma unroll
    for (int i = 0; i < 4; ++i)
#pragma unroll
      for (int j = 0; j < 4; ++j)
        acc[i][j] = __builtin_amdgcn_mfma_f32_16x16x32_f16(af[i], bf[j], acc[i][j], 0, 0, 0);
    __syncthreads();
  }

  float bj[4];
#pragma unroll
  for (int j = 0; j < 4; ++j) bj[j] = bias[n0 + wc * 64 + j * 16 + r16];
#pragma unroll
  for (int i = 0; i < 4; ++i) {
    const long mb = m0 + wr * 64 + i * 16 + g8 * 4;
#pragma unroll
    for (int j = 0; j < 4; ++j) {
      const long nn = n0 + wc * 64 + j * 16 + r16;
#pragma unroll
      for (int r = 0; r < 4; ++r)
        out[(mb + r) * D_ + nn] = acc[i][j][r] + bj[j];
    }
  }
}

// ---------------------------------------------------------------- phase 2
// 256 WGs x 256 threads (1/CU). Group mapping keeps a group's 16 ranks on one
// XCD under round-robin (perf heuristic only): g = (bid&7)*2 + ((bid>>3)&1),
// rk = bid>>4. Batches b0..b0+4 (b0=g*4), cols j0..j0+64 (j0=rk*64).
// Wave w: polls k-quarter w (8 u64/lane), stages to Hb[t&1] (XOR-swizzled),
// one barrier, then n-tile w (16 j) over FULL K: 32 MFMA in 4 indep chains,
// in-register k-sum, shuffle-redistribute, epilogue, publish. LDS = 16 KB.
__global__ __launch_bounds__(256, 1) void k_recur(
    const f16* __restrict__ wh16, u64* slots, const float* __restrict__ z,
    const float* __restrict__ h0, const float* __restrict__ alpha,
    float* __restrict__ out) {
  __shared__ char Hb[2][8192];

  const int tid = threadIdx.x, lane = tid & 63, w = tid >> 6;
  const int bid = blockIdx.x;
  const int g = (bid & 7) * 2 + ((bid >> 3) & 1);
  const int rk = bid >> 4;
  const int j0 = rk * 64, b0 = g * 4;

  // register-resident Wh B-frags: n-tile w (cols j0+w*16..+16), full K
  // bfr[kt] elem e: Wh[col = j0+w*16+(lane&15)][k = kt*32 + (lane>>4)*8 + e]
  f16x8 bfr[32];
  {
    const f16* wb = wh16 + (long)(j0 + w * 16 + (lane & 15)) * D_ + (lane >> 4) * 8;
#pragma unroll
    for (int kt = 0; kt < 32; ++kt)
      bfr[kt] = *(const f16x8*)(wb + kt * 32);
  }

  const int bl = lane >> 4;   // epilogue ownership: batch 0..3
  const int jl = lane & 15;   // epilogue ownership: j within n-tile
  const int jj = j0 + w * 16 + jl;
  const float lk = 1.0f - alpha[jj];
  float hp = h0[(long)(b0 + bl) * D_ + jj];

  const int ab = lane & 3;    // af source batch row (rows 4..15 = dups)
  const int g8 = lane >> 4;

  for (int t = 0; t < T_; ++t) {
    const long off = ((long)(b0 + bl) * T_ + t) * D_ + jj;
    // prefetch (in flight during poll; consumed in epilogue)
    float A = out[off];
    float Z = z[off];

    // ---- fence-free tagged poll of k-quarter w: 8 u64/lane ----
    const u64* cur = slots + (long)(t & 1) * 32768 + (long)b0 * 512 + w * 128;
    u64 vv[8];
    unsigned pend = 0xFFu;
    for (int guard = 0; pend && guard < (1 << 18); ++guard) {
#pragma unroll
      for (int i = 0; i < 8; ++i)
        if (pend & (1u << i)) {
          const int idx = i * 64 + lane;
          vv[i] = __hip_atomic_load(cur + (idx >> 7) * 512 + (idx & 127),
                                    __ATOMIC_RELAXED, __HIP_MEMORY_SCOPE_AGENT);
        }
#pragma unroll
      for (int i = 0; i < 8; ++i)
        if ((pend & (1u << i)) && (unsigned)(vv[i] >> 32) == (unsigned)t)
          pend &= ~(1u << i);
    }

    // ---- stage quarter into Hb[t&1]: linear o = pair*4, XOR b*32 ----
    char* hb = Hb[t & 1];
#pragma unroll
    for (int i = 0; i < 8; ++i) {
      const int idx = i * 64 + lane, b = idx >> 7, lp = idx & 127;
      const int o = w * 512 + lp * 4;
      *(unsigned*)(hb + b * 2048 + (o ^ (b * 32))) = (unsigned)vv[i];
    }
    __syncthreads();  // the ONLY barrier per step

    // ---- full-K MFMA for n-tile w: 4 independent sub-chains of 8 ----
    f32x4 ac0 = {}, ac1 = {}, ac2 = {}, ac3 = {};
#pragma unroll
    for (int kt = 0; kt < 32; kt += 4) {
      f16x8 a0 = *(const f16x8*)(hb + ab * 2048 + (((kt + 0) * 64 + g8 * 16) ^ (ab * 32)));
      f16x8 a1 = *(const f16x8*)(hb + ab * 2048 + (((kt + 1) * 64 + g8 * 16) ^ (ab * 32)));
      f16x8 a2 = *(const f16x8*)(hb + ab * 2048 + (((kt + 2) * 64 + g8 * 16) ^ (ab * 32)));
      f16x8 a3 = *(const f16x8*)(hb + ab * 2048 + (((kt + 3) * 64 + g8 * 16) ^ (ab * 32)));
      ac0 = __builtin_amdgcn_mfma_f32_16x16x32_f16(a0, bfr[kt + 0], ac0, 0, 0, 0);
      ac1 = __builtin_amdgcn_mfma_f32_16x16x32_f16(a1, bfr[kt + 1], ac1, 0, 0, 0);
      ac2 = __builtin_amdgcn_mfma_f32_16x16x32_f16(a2, bfr[kt + 2], ac2, 0, 0, 0);
      ac3 = __builtin_amdgcn_mfma_f32_16x16x32_f16(a3, bfr[kt + 3], ac3, 0, 0, 0);
    }
    const f32x4 facc = (ac0 + ac1) + (ac2 + ac3);

    // ---- redistribute: lane m gets facc[m>>4] from lane m&15 ----
    const float v0 = __shfl(facc[0], jl);
    const float v1 = __shfl(facc[1], jl);
    const float v2 = __shfl(facc[2], jl);
    const float v3 = __shfl(facc[3], jl);
    const float pre = bl == 0 ? v0 : bl == 1 ? v1 : bl == 2 ? v2 : v3;

    // ---- epilogue (fast exp forms; args bounded) ----
    const float gg = __builtin_amdgcn_rcpf(1.0f + __expf(-(pre + A)));
    float y = 2.0f * (hp * lk + gg * Z);
    y = fminf(fmaxf(y, -30.0f), 30.0f);
    const float ex = __expf(y);
    const float hn = (ex - 1.0f) * __builtin_amdgcn_rcpf(ex + 1.0f);
    hp = hn;

    // ---- publish tagged pairs first (critical path), then out store ----
    const float q = __shfl_xor(hn, 1);
    if (!(lane & 1)) {
      f16 pa = (f16)hn, pb = (f16)q;
      const unsigned u = (unsigned)*(unsigned short*)&pa |
                         ((unsigned)*(unsigned short*)&pb << 16);
      const u64 val = (((u64)(unsigned)(t + 1)) << 32) | (u64)u;
      __hip_atomic_store(
          slots + (long)((t + 1) & 1) * 32768 + (long)(b0 + bl) * 512 +
              (j0 >> 1) + w * 8 + (jl >> 1),
          val, __ATOMIC_RELAXED, __HIP_MEMORY_SCOPE_AGENT);
    }
    out[off] = hn;  // overwrite A slot in place
  }
}

// ---------------------------------------------------------------- launcher
extern "C" void kernel_launch(void* const* d_in, const int* in_sizes, int n_in,
                              void* d_out, int out_size, void* d_ws, size_t ws_size,
                              hipStream_t stream) {
  const float* h_t = (const float*)d_in[0];
  const float* z = (const float*)d_in[1];
  const float* W = (const float*)d_in[2];
  const float* bias = (const float*)d_in[3];
  const float* alpha = (const float*)d_in[4];
  float* out = (float*)d_out;
  char* ws = (char*)d_ws;
  f16* z16 = (f16*)(ws + WS_Z16);
  f16* wh16 = (f16*)(ws + WS_WH16);
  f16* wz16 = (f16*)(ws + WS_WZ16);
  u64* slots = (u64*)(ws + WS_SLOTS);
  // requires ws_size >= 71,827,456 bytes

  k_prep<<<dim3(2048), dim3(256), 0, stream>>>(z, W, h_t, z16, wh16, wz16, slots);
  k_gemm_zw<<<dim3(2048), dim3(256), 0, stream>>>(z16, wz16, bias, out);
  k_recur<<<dim3(256), dim3(256), 0, stream>>>(wh16, slots, z, h_t, alpha, out);
}

// Round 7
// 1359.524 us; speedup vs baseline: 1.3256x; 1.3256x over previous
//
#include <hip/hip_runtime.h>
#include <math.h>

// LatentDynamics: out[b,t,:] = scan of h' = tanh(h*leak + sigmoid(h@Wh^T + z_t@Wz^T + b)*z_t)
// B=64, T=512, D=1024.
//
// Phase 0 (k_prep):   fp32->f16 W split (Wh/Wz); init exchange slots (parity0 = h0 tag 0,
//                     parity1 = sentinel) -- re-run every launch (graph-safe).
// Phase 1 (k_gemm_zw): A[m,j] = z[m,:]@Wz^T[j,:] + bias[j] -> d_out (in-place slot for h).
// Phase 2 (k_recur):  256 persistent WGs = 16 groups (4 batches) x 16 ranks (64 j).
//                     k-split: wave w owns k-quarter (poll 8 u64/lane, wave-local stage,
//                     8 af reads reused x4 n-tiles, 32 MFMA). Cross-wave k-reduce through
//                     conflict-free padded LDS, parity double-buffered -> ONE barrier/step.
//                     Fence-free tagged u64 slots ([tag32 | 2xf16], relaxed agent atomics).

#define D_ 1024
#define B_ 64
#define T_ 512

typedef _Float16 f16;
typedef _Float16 f16x8 __attribute__((ext_vector_type(8)));
typedef _Float16 f16x4 __attribute__((ext_vector_type(4)));
typedef float f32x4 __attribute__((ext_vector_type(4)));
typedef unsigned long long u64;

// workspace layout (bytes); total 4,718,592 (4.5 MB)
#define WS_WH16  0L
#define WS_WZ16  2097152L
#define WS_SLOTS 4194304L
// slots: u64[2][64][512]  (parity, batch, j-pair)

__device__ __forceinline__ void gload_lds16(const void* g, void* l) {
  __builtin_amdgcn_global_load_lds(
      (const __attribute__((address_space(1))) void*)(g),
      (__attribute__((address_space(3))) void*)(l), 16, 0, 0);
}

// ---------------------------------------------------------------- phase 0
__global__ __launch_bounds__(256) void k_prep(
    const float* __restrict__ W, const float* __restrict__ h0,
    f16* __restrict__ wh16, f16* __restrict__ wz16, u64* __restrict__ slots) {
  const int tid = blockIdx.x * 256 + threadIdx.x;  // grid = 2048*256 = 524288
  {
    const long e = (long)tid * 4;
    const long j = e >> 11, c = e & 2047;
    float4 v = *(const float4*)(W + e);
    f16x4 o = {(f16)v.x, (f16)v.y, (f16)v.z, (f16)v.w};
    f16* dst = (c < D_) ? (wh16 + j * D_ + c) : (wz16 + j * D_ + (c - D_));
    *(f16x4*)dst = o;
  }
  if (tid < 65536) {
    if (tid < 32768) {  // parity 0 <- h0, tag 0
      const int b = tid >> 9, p = tid & 511;
      f16 fa = (f16)h0[(long)b * D_ + 2 * p];
      f16 fb = (f16)h0[(long)b * D_ + 2 * p + 1];
      unsigned u = (unsigned)*(unsigned short*)&fa |
                   ((unsigned)*(unsigned short*)&fb << 16);
      slots[tid] = (u64)u;
    } else {
      slots[tid] = 0xFFFFFFFF00000000ull;  // parity 1 sentinel
    }
  }
}

// ---------------------------------------------------------------- phase 1
// 128x128 tile, 4 waves (2x2), BK=32. A reg-staged from fp32 z (convert inline),
// B (Wz f16) via global_load_lds. 2 barriers per K-step. (round-4 validated)
__global__ __launch_bounds__(256) void k_gemm_zw(
    const float* __restrict__ zf, const f16* __restrict__ wz16,
    const float* __restrict__ bias, float* __restrict__ out) {
  __shared__ f16 ldsA[8 * 512];
  __shared__ f16 ldsB[8 * 512];
  const int tid = threadIdx.x, lane = tid & 63, w = tid >> 6;
  const int r16 = lane & 15, g8 = lane >> 4;
  const int nt = blockIdx.x & 7, mt = blockIdx.x >> 3;
  const long m0 = (long)mt * 128, n0 = (long)nt * 128;
  const int arow = tid >> 1, kh = (tid & 1) * 16;
  const float* gA = zf + (m0 + arow) * D_ + kh;
  const f16* gB = wz16 + (n0 + r16) * D_ + g8 * 8;
  const int wr = w >> 1, wc = w & 1;
  f32x4 acc[4][4] = {};
  float4 ra[4];
#pragma unroll
  for (int q = 0; q < 4; ++q) ra[q] = *(const float4*)(gA + q * 4);

  for (int ks = 0; ks < 32; ++ks) {
    if (ks) __syncthreads();
#pragma unroll
    for (int c = 0; c < 2; ++c) {
      const int ch = w * 2 + c;
      gload_lds16(gB + (long)ch * 16 * D_ + ks * 32, &ldsB[ch * 512]);
    }
    {
      const int ch = arow >> 4, lr = arow & 15;
#pragma unroll
      for (int hf = 0; hf < 2; ++hf) {
        float4 x = ra[hf * 2], y = ra[hf * 2 + 1];
        f16x8 v = {(f16)x.x, (f16)x.y, (f16)x.z, (f16)x.w,
                   (f16)y.x, (f16)y.y, (f16)y.z, (f16)y.w};
        const int kk = kh + hf * 8;
        *(f16x8*)(&ldsA[ch * 512 + (lr | ((kk >> 3) << 4)) * 8]) = v;
      }
    }
    __syncthreads();
    if (ks < 31) {
#pragma unroll
      for (int q = 0; q < 4; ++q)
        ra[q] = *(const float4*)(gA + (ks + 1) * 32 + q * 4);
    }
    f16x8 af[4], bf[4];
#pragma unroll
    for (int i = 0; i < 4; ++i)
      af[i] = *(const f16x8*)(&ldsA[(wr * 4 + i) * 512 + lane * 8]);
#pragma unroll
    for (int j = 0; j < 4; ++j)
      bf[j] = *(const f16x8*)(&ldsB[(wc * 4 + j) * 512 + lane * 8]);
#pragma unroll
    for (int i = 0; i < 4; ++i)
#pragma unroll
      for (int j = 0; j < 4; ++j)
        acc[i][j] = __builtin_amdgcn_mfma_f32_16x16x32_f16(af[i], bf[j], acc[i][j], 0, 0, 0);
  }

  float bj[4];
#pragma unroll
  for (int j = 0; j < 4; ++j) bj[j] = bias[n0 + wc * 64 + j * 16 + r16];
#pragma unroll
  for (int i = 0; i < 4; ++i) {
    const long mb = m0 + wr * 64 + i * 16 + g8 * 4;
#pragma unroll
    for (int j = 0; j < 4; ++j) {
      const long nn = n0 + wc * 64 + j * 16 + r16;
#pragma unroll
      for (int r = 0; r < 4; ++r)
        out[(mb + r) * D_ + nn] = acc[i][j][r] + bj[j];
    }
  }
}

// ---------------------------------------------------------------- phase 2
// 256 WGs x 256 threads (1/CU). g = (bid&7)*2 + ((bid>>3)&1), rk = bid>>4.
// Batches b0..b0+4 (b0=g*4), cols j0..j0+64 (j0=rk*64).
// Wave w = k-quarter: poll 8 u64/lane -> wave-local stage -> 8 af reads x4 n
// (32 MFMA) -> red write (1 scalar/lane/n, reg r=g8) -> B1 -> contiguous
// reduce read -> fast epilogue -> publish -> out store. ONE barrier/step.
// LDS: Hb 8 KB + Rd[2] 10 KB = 18 KB.
__global__ __launch_bounds__(256, 1) void k_recur(
    const f16* __restrict__ wh16, u64* slots, const float* __restrict__ z,
    const float* __restrict__ h0, const float* __restrict__ alpha,
    float* __restrict__ out) {
  __shared__ char Hb[8192];
  __shared__ char Rd[2][5120];  // [par][kq*1280 + r*320 + n*64 + col*4]

  const int tid = threadIdx.x, lane = tid & 63, w = tid >> 6;
  const int bid = blockIdx.x;
  const int g = (bid & 7) * 2 + ((bid >> 3) & 1);
  const int rk = bid >> 4;
  const int j0 = rk * 64, b0 = g * 4;

  // register-resident Wh B-frags: wave w, n-tile n, k-step kt
  // elem: Wh[col = j0+n*16+(lane&15)][k = w*256 + kt*32 + (lane>>4)*8 + e]
  f16x8 bfr[32];
  {
    const f16* wb = wh16 + (long)(j0 + (lane & 15)) * D_ + w * 256 + (lane >> 4) * 8;
#pragma unroll
    for (int n = 0; n < 4; ++n)
#pragma unroll
      for (int kt = 0; kt < 8; ++kt)
        bfr[n * 8 + kt] = *(const f16x8*)(wb + (long)n * 16 * D_ + kt * 32);
  }

  const int jj = j0 + lane;
  const float lk = 1.0f - alpha[jj];
  float hp = h0[(long)(b0 + w) * D_ + jj];

  const int row = lane & 3, g8 = lane >> 4;

  for (int t = 0; t < T_; ++t) {
    const long off = ((long)(b0 + w) * T_ + t) * D_ + jj;
    // prefetch (in flight during poll; consumed in epilogue)
    float A = out[off];
    float Z = z[off];

    // ---- fence-free tagged poll of k-quarter w: 8 u64/lane ----
    const u64* cur = slots + (long)(t & 1) * 32768 + (long)b0 * 512 + w * 128;
    u64 vv[8];
    unsigned pend = 0xFFu;
    for (int guard = 0; pend && guard < (1 << 18); ++guard) {
#pragma unroll
      for (int i = 0; i < 8; ++i)
        if (pend & (1u << i)) {
          const int idx = i * 64 + lane;
          vv[i] = __hip_atomic_load(cur + (idx >> 7) * 512 + (idx & 127),
                                    __ATOMIC_RELAXED, __HIP_MEMORY_SCOPE_AGENT);
        }
#pragma unroll
      for (int i = 0; i < 8; ++i)
        if ((pend & (1u << i)) && (unsigned)(vv[i] >> 32) == (unsigned)t)
          pend &= ~(1u << i);
    }

    // ---- stage own quarter (wave-local; no barrier before MFMA) ----
#pragma unroll
    for (int i = 0; i < 8; ++i) {
      const int idx = i * 64 + lane, b = idx >> 7, lp = idx & 127;
      *(unsigned*)(Hb + ((w * 2048 + b * 512 + lp * 4) ^ ((b & 1) << 6))) =
          (unsigned)vv[i];
    }

    // ---- MFMA: 8 kt, each af read feeds 4 n-tiles (rows 4-15 = dups) ----
    f32x4 acc[4] = {{0,0,0,0},{0,0,0,0},{0,0,0,0},{0,0,0,0}};
#pragma unroll
    for (int kt = 0; kt < 8; ++kt) {
      f16x8 af = *(const f16x8*)(
          Hb + ((w * 2048 + row * 512 + kt * 64 + g8 * 16) ^ ((row & 1) << 6)));
#pragma unroll
      for (int n = 0; n < 4; ++n)
        acc[n] = __builtin_amdgcn_mfma_f32_16x16x32_f16(af, bfr[n * 8 + kt], acc[n], 0, 0, 0);
    }

    // ---- red write: lane stores reg r=g8 (dup C-rows make this complete) ----
    // layout byte = kq*1280 + r*320 + n*64 + col*4  (<=2-way banks both sides)
    char* rd = Rd[t & 1];
#pragma unroll
    for (int n = 0; n < 4; ++n) {
      const f32x4 v = acc[n];
      const float val = (g8 & 1) ? ((g8 & 2) ? v[3] : v[1])
                                 : ((g8 & 2) ? v[2] : v[0]);
      *(float*)(rd + w * 1280 + g8 * 320 + n * 64 + (lane & 15) * 4) = val;
    }
    __syncthreads();  // the ONLY barrier per step

    // ---- reduce read: contiguous 256B per instr; thread owns (b0+w, jj) ----
    float pre = 0.f;
#pragma unroll
    for (int kq = 0; kq < 4; ++kq)
      pre += *(const float*)(rd + kq * 1280 + w * 320 + lane * 4);

    // ---- fast epilogue (args bounded; validated absmax 0.0039) ----
    const float gg = __builtin_amdgcn_rcpf(1.0f + __expf(-(pre + A)));
    float y = 2.0f * (hp * lk + gg * Z);
    y = fminf(fmaxf(y, -30.0f), 30.0f);
    const float ex = __expf(y);
    const float hn = (ex - 1.0f) * __builtin_amdgcn_rcpf(ex + 1.0f);
    hp = hn;

    // ---- publish tagged pairs first (critical path), then out store ----
    const float q = __shfl_xor(hn, 1);
    if (!(lane & 1)) {
      f16 pa = (f16)hn, pb = (f16)q;
      const unsigned u = (unsigned)*(unsigned short*)&pa |
                         ((unsigned)*(unsigned short*)&pb << 16);
      const u64 val = (((u64)(unsigned)(t + 1)) << 32) | (u64)u;
      __hip_atomic_store(
          slots + (long)((t + 1) & 1) * 32768 + (long)(b0 + w) * 512 + (jj >> 1),
          val, __ATOMIC_RELAXED, __HIP_MEMORY_SCOPE_AGENT);
    }
    out[off] = hn;  // overwrite A slot in place
  }
}

// ---------------------------------------------------------------- launcher
extern "C" void kernel_launch(void* const* d_in, const int* in_sizes, int n_in,
                              void* d_out, int out_size, void* d_ws, size_t ws_size,
                              hipStream_t stream) {
  const float* h_t = (const float*)d_in[0];
  const float* z = (const float*)d_in[1];
  const float* W = (const float*)d_in[2];
  const float* bias = (const float*)d_in[3];
  const float* alpha = (const float*)d_in[4];
  float* out = (float*)d_out;
  char* ws = (char*)d_ws;
  f16* wh16 = (f16*)(ws + WS_WH16);
  f16* wz16 = (f16*)(ws + WS_WZ16);
  u64* slots = (u64*)(ws + WS_SLOTS);
  // requires ws_size >= 4,718,592 bytes

  k_prep<<<dim3(2048), dim3(256), 0, stream>>>(W, h_t, wh16, wz16, slots);
  k_gemm_zw<<<dim3(2048), dim3(256), 0, stream>>>(z, wz16, bias, out);
  k_recur<<<dim3(256), dim3(256), 0, stream>>>(wh16, slots, z, h_t, alpha, out);
}